// Round 1
// 387.354 us; speedup vs baseline: 1.0168x; 1.0168x over previous
//
#include <hip/hip_runtime.h>

#define H_DIM 128
#define L_SESS 50
#define B_SESS 10000
#define NBLK 768    // persistent blocks: 3/CU x 256 CU (VGPR-limited at (256,3))
#define NITER 14    // ceil(B_SESS / NBLK)
#define LDSTR 136   // Xb row stride in bf16 elems (128+8 pad)
#define ESTR 5      // epart row stride in floats

typedef __bf16 bf16_t;
typedef __bf16 bf16x8 __attribute__((ext_vector_type(8)));
typedef float f32x4 __attribute__((ext_vector_type(4)));

__device__ __forceinline__ bf16x8 cvt_bf8(float4 a, float4 b) {
  bf16x8 r;
  r[0] = (bf16_t)a.x; r[1] = (bf16_t)a.y; r[2] = (bf16_t)a.z; r[3] = (bf16_t)a.w;
  r[4] = (bf16_t)b.x; r[5] = (bf16_t)b.y; r[6] = (bf16_t)b.z; r[7] = (bf16_t)b.w;
  return r;
}

// Single fused persistent kernel:
//  - W1/W2 fragments fp32->bf16 once per block (replaces cvt_kernel + W2bf ws)
//  - u[n] = W1[n].x_last + b computed via broadcast-row MFMA from Xb row 49
//    (replaces sess_u_kernel + the 5.12MB U round-trip)
//  - GEMM/softmax/pooling core identical to the verified r-prev kernel
__global__ __launch_bounds__(256, 3) void fused_attn_kernel(
    const float* __restrict__ x, const float* __restrict__ w1,
    const float* __restrict__ w1b, const float* __restrict__ w2,
    const float* __restrict__ w2bi, const float* __restrict__ qw,
    const float* __restrict__ qb, float* __restrict__ out) {
  __shared__ __attribute__((aligned(16))) unsigned short Xb[64 * LDSTR];
  __shared__ float epart[64 * ESTR];
  __shared__ float alpha_s[64];

  const int t = threadIdx.x;
  const int lane = t & 63, w = t >> 6, q = lane >> 4, c = lane & 15;
  const int n0 = w * 32 + c, n1 = n0 + 16;

  // prologue: issue session-s x loads FIRST (HBM latency hides under weight setup)
  int s = blockIdx.x;
  int sc = (s < B_SESS) ? s : (B_SESS - 1);
  const float4* xv = (const float4*)(x + (size_t)sc * (L_SESS * H_DIM));
  float4 v[6];
#pragma unroll
  for (int j = 0; j < 6; ++j) v[j] = xv[t + 256 * j];
  float4 v6;
  if (t < 64) v6 = xv[1536 + t];

  // loop-invariant weight fragments: fp32 global (L2-hot, 128KB/block once) -> bf16 regs
  bf16x8 bw2[4][2], bw1[4][2];
  const float4* w2v = (const float4*)w2;
  const float4* w1v = (const float4*)w1;
#pragma unroll
  for (int kt = 0; kt < 4; ++kt) {
    const int ko4 = kt * 8 + q * 2;  // float4 index within a 128-float row
    bw2[kt][0] = cvt_bf8(w2v[n0 * 32 + ko4], w2v[n0 * 32 + ko4 + 1]);
    bw2[kt][1] = cvt_bf8(w2v[n1 * 32 + ko4], w2v[n1 * 32 + ko4 + 1]);
    bw1[kt][0] = cvt_bf8(w1v[n0 * 32 + ko4], w1v[n0 * 32 + ko4 + 1]);
    bw1[kt][1] = cvt_bf8(w1v[n1 * 32 + ko4], w1v[n1 * 32 + ko4 + 1]);
  }
  const float qn0 = qw[n0], qn1 = qw[n1], qbv = qb[0];
  const float b0 = w1b[n0] + w2bi[n0];
  const float b1 = w1b[n1] + w2bi[n1];

  const f32x4 zero4 = {0.f, 0.f, 0.f, 0.f};

  for (int it = 0; it < NITER; ++it) {
    __syncthreads();  // prev pooling done reading Xb

    // convert prefetch registers -> bf16 LDS
#pragma unroll
    for (int j = 0; j < 6; ++j) {
      int i = t + 256 * j;
      int row = i >> 5, col = (i & 31) * 4;
      union { bf16_t h[4]; ushort4 u4; } tmp;
      tmp.h[0] = (bf16_t)v[j].x; tmp.h[1] = (bf16_t)v[j].y;
      tmp.h[2] = (bf16_t)v[j].z; tmp.h[3] = (bf16_t)v[j].w;
      *(ushort4*)&Xb[row * LDSTR + col] = tmp.u4;
    }
    if (t < 64) {
      int i = 1536 + t;
      int row = i >> 5, col = (i & 31) * 4;
      union { bf16_t h[4]; ushort4 u4; } tmp;
      tmp.h[0] = (bf16_t)v6.x; tmp.h[1] = (bf16_t)v6.y;
      tmp.h[2] = (bf16_t)v6.z; tmp.h[3] = (bf16_t)v6.w;
      *(ushort4*)&Xb[row * LDSTR + col] = tmp.u4;
    }
    __syncthreads();

    // issue NEXT session's loads (in flight across u-MFMA/GEMM/epilogue/pool)
    if (it + 1 < NITER) {
      int sn = s + NBLK;
      int snc = (sn < B_SESS) ? sn : (B_SESS - 1);
      const float4* xn = (const float4*)(x + (size_t)snc * (L_SESS * H_DIM));
#pragma unroll
      for (int j = 0; j < 6; ++j) v[j] = xn[t + 256 * j];
      if (t < 64) v6 = xn[1536 + t];
    }

    // u[n] = W1[n] . x_last via broadcast-row MFMA: all 16 A-rows = Xb row 49
    // (16-lane same-address LDS read = free broadcast; D rows all identical)
    f32x4 uacc0 = zero4, uacc1 = zero4;
#pragma unroll
    for (int kt = 0; kt < 4; ++kt) {
      bf16x8 av = *(const bf16x8*)&Xb[49 * LDSTR + kt * 32 + q * 8];
      uacc0 = __builtin_amdgcn_mfma_f32_16x16x32_bf16(av, bw1[kt][0], uacc0, 0, 0, 0);
      uacc1 = __builtin_amdgcn_mfma_f32_16x16x32_bf16(av, bw1[kt][1], uacc1, 0, 0, 0);
    }
    const float u0 = uacc0[0] + b0;  // any reg works: rows identical
    const float u1 = uacc1[0] + b1;

    // GEMM: D[64x32]/wave = Xb(64x128) @ W2^T cols (B in registers)
    f32x4 acc[4][2];
#pragma unroll
    for (int mt = 0; mt < 4; ++mt) { acc[mt][0] = zero4; acc[mt][1] = zero4; }
#pragma unroll
    for (int kt = 0; kt < 4; ++kt) {
      const int ko = kt * 32 + q * 8;
#pragma unroll
      for (int mt = 0; mt < 4; ++mt) {
        bf16x8 a = *(const bf16x8*)&Xb[(mt * 16 + c) * LDSTR + ko];
        acc[mt][0] = __builtin_amdgcn_mfma_f32_16x16x32_bf16(a, bw2[kt][0], acc[mt][0], 0, 0, 0);
        acc[mt][1] = __builtin_amdgcn_mfma_f32_16x16x32_bf16(a, bw2[kt][1], acc[mt][1], 0, 0, 0);
      }
    }

    // epilogue: h=sigmoid(acc+u); per-(row,wave) e-partials via shfl over cols
#pragma unroll
    for (int mt = 0; mt < 4; ++mt) {
#pragma unroll
      for (int r = 0; r < 4; ++r) {
        float t0 = acc[mt][0][r] + u0;
        float t1 = acc[mt][1][r] + u1;
        float h0 = 1.0f / (1.0f + __expf(-t0));
        float h1 = 1.0f / (1.0f + __expf(-t1));
        float p = h0 * qn0 + h1 * qn1;
#pragma unroll
        for (int off = 1; off <= 8; off <<= 1) p += __shfl_xor(p, off);
        if (c == 0) epart[(mt * 16 + q * 4 + r) * ESTR + w] = p;  // row=q*4+r
      }
    }
    __syncthreads();

    // wave 0: masked stable softmax over the 50 real rows
    if (t < 64) {
      float e = qbv;
#pragma unroll
      for (int j = 0; j < 4; ++j) e += epart[t * ESTR + j];
      float val = (t < L_SESS) ? e : -1.0e30f;
      float mx = val;
#pragma unroll
      for (int off = 32; off > 0; off >>= 1) mx = fmaxf(mx, __shfl_xor(mx, off));
      float z = (t < L_SESS) ? __expf(e - mx) : 0.f;
      float d = z;
#pragma unroll
      for (int off = 32; off > 0; off >>= 1) d += __shfl_xor(d, off);
      alpha_s[t] = z / d;
    }
    __syncthreads();

    // pooling from LDS bf16: 128 threads, one column each
    if (t < H_DIM) {
      float acc_p = 0.f;
#pragma unroll
      for (int m = 0; m < L_SESS; ++m) {
        unsigned short pv = Xb[m * LDSTR + t];
        acc_p += alpha_s[m] * __uint_as_float(((unsigned int)pv) << 16);
      }
      if (s < B_SESS) out[(size_t)s * H_DIM + t] = acc_p;
    }
    s += NBLK;
  }
}

extern "C" void kernel_launch(void* const* d_in, const int* in_sizes, int n_in,
                              void* d_out, int out_size, void* d_ws, size_t ws_size,
                              hipStream_t stream) {
  const float* x    = (const float*)d_in[0];
  const float* w1   = (const float*)d_in[1];
  const float* w1b  = (const float*)d_in[2];
  const float* w2   = (const float*)d_in[3];
  const float* w2bi = (const float*)d_in[4];
  const float* qw   = (const float*)d_in[5];
  const float* qb   = (const float*)d_in[6];
  fused_attn_kernel<<<NBLK, 256, 0, stream>>>(x, w1, w1b, w2, w2bi, qw, qb,
                                              (float*)d_out);
}

// Round 2
// 378.254 us; speedup vs baseline: 1.0413x; 1.0241x over previous
//
#include <hip/hip_runtime.h>

#define H_DIM 128
#define L_SESS 50
#define B_SESS 10000
#define NBLK 768    // persistent blocks: 3/CU x 256 CU
#define NITER 14    // ceil(B_SESS / NBLK)
#define LDSTR 136   // Xb row stride in bf16 elems (128+8 pad)
#define ESTR 5      // epart row stride in floats
#define POOLSTR 132 // pool row stride in floats (128+4 pad)

typedef __bf16 bf16_t;
typedef __bf16 bf16x8 __attribute__((ext_vector_type(8)));
typedef float f32x4 __attribute__((ext_vector_type(4)));

__device__ __forceinline__ bf16x8 cvt_bf8(float4 a, float4 b) {
  bf16x8 r;
  r[0] = (bf16_t)a.x; r[1] = (bf16_t)a.y; r[2] = (bf16_t)a.z; r[3] = (bf16_t)a.w;
  r[4] = (bf16_t)b.x; r[5] = (bf16_t)b.y; r[6] = (bf16_t)b.z; r[7] = (bf16_t)b.w;
  return r;
}

// DPP row_ror reductions: pure-VALU cross-lane within each 16-lane row (no DS)
template <int CTRL>
__device__ __forceinline__ float dpp_add(float x) {
  int tt = __builtin_amdgcn_update_dpp(0, __float_as_int(x), CTRL, 0xF, 0xF, false);
  return x + __int_as_float(tt);
}
template <int CTRL>
__device__ __forceinline__ float dpp_max(float x) {
  int tt = __builtin_amdgcn_update_dpp(0, __float_as_int(x), CTRL, 0xF, 0xF, false);
  return fmaxf(x, __int_as_float(tt));
}
__device__ __forceinline__ float row16_sum(float x) {
  x = dpp_add<0x121>(x); x = dpp_add<0x122>(x);  // row_ror:1, :2
  x = dpp_add<0x124>(x); x = dpp_add<0x128>(x);  // row_ror:4, :8
  return x;
}
__device__ __forceinline__ float wave_sum(float x) {
  x = row16_sum(x);
  x += __shfl_xor(x, 16);
  x += __shfl_xor(x, 32);
  return x;
}
__device__ __forceinline__ float wave_max(float x) {
  x = dpp_max<0x121>(x); x = dpp_max<0x122>(x);
  x = dpp_max<0x124>(x); x = dpp_max<0x128>(x);
  x = fmaxf(x, __shfl_xor(x, 16));
  x = fmaxf(x, __shfl_xor(x, 32));
  return x;
}

__global__ __launch_bounds__(256, 3) void fused_attn_kernel(
    const float* __restrict__ x, const float* __restrict__ w1,
    const float* __restrict__ w1b, const float* __restrict__ w2,
    const float* __restrict__ w2bi, const float* __restrict__ qw,
    const float* __restrict__ qb, float* __restrict__ out) {
  __shared__ __attribute__((aligned(16))) unsigned short Xb[64 * LDSTR];
  __shared__ __attribute__((aligned(16))) float epart[64 * ESTR];
  __shared__ __attribute__((aligned(16))) float pool[4 * POOLSTR];

  const int t = threadIdx.x;
  const int lane = t & 63, w = t >> 6, q = lane >> 4, c = lane & 15;
  const int wu = __builtin_amdgcn_readfirstlane(w);  // SGPR wave id
  const int n0 = w * 32 + c, n1 = n0 + 16;

  // prologue: issue session-s x loads FIRST (HBM latency hides under setup)
  int s = blockIdx.x;
  int sc = (s < B_SESS) ? s : (B_SESS - 1);
  const float4* xv = (const float4*)(x + (size_t)sc * (L_SESS * H_DIM));
  float4 v[6];
#pragma unroll
  for (int j = 0; j < 6; ++j) v[j] = xv[t + 256 * j];
  float4 v6;
  if (t < 64) v6 = xv[1536 + t];

  // loop-invariant weight fragments: fp32 global (L2-hot) -> bf16 regs
  bf16x8 bw2[4][2], bw1[4][2];
  const float4* w2v = (const float4*)w2;
  const float4* w1v = (const float4*)w1;
#pragma unroll
  for (int kt = 0; kt < 4; ++kt) {
    const int ko4 = kt * 8 + q * 2;
    bw2[kt][0] = cvt_bf8(w2v[n0 * 32 + ko4], w2v[n0 * 32 + ko4 + 1]);
    bw2[kt][1] = cvt_bf8(w2v[n1 * 32 + ko4], w2v[n1 * 32 + ko4 + 1]);
    bw1[kt][0] = cvt_bf8(w1v[n0 * 32 + ko4], w1v[n0 * 32 + ko4 + 1]);
    bw1[kt][1] = cvt_bf8(w1v[n1 * 32 + ko4], w1v[n1 * 32 + ko4 + 1]);
  }
  const float qn0 = qw[n0], qn1 = qw[n1], qbv = qb[0];
  const float b0 = w1b[n0] + w2bi[n0];
  const float b1 = w1b[n1] + w2bi[n1];

  const f32x4 zero4 = {0.f, 0.f, 0.f, 0.f};

  for (int it = 0; it < NITER; ++it) {
    __syncthreads();  // prev iter done reading Xb

    // stage prefetch registers -> bf16 LDS
#pragma unroll
    for (int j = 0; j < 6; ++j) {
      int i = t + 256 * j;
      int row = i >> 5, col = (i & 31) * 4;
      union { bf16_t h[4]; ushort4 u4; } tmp;
      tmp.h[0] = (bf16_t)v[j].x; tmp.h[1] = (bf16_t)v[j].y;
      tmp.h[2] = (bf16_t)v[j].z; tmp.h[3] = (bf16_t)v[j].w;
      *(ushort4*)&Xb[row * LDSTR + col] = tmp.u4;
    }
    if (t < 64) {
      int i = 1536 + t;
      int row = i >> 5, col = (i & 31) * 4;
      union { bf16_t h[4]; ushort4 u4; } tmp;
      tmp.h[0] = (bf16_t)v6.x; tmp.h[1] = (bf16_t)v6.y;
      tmp.h[2] = (bf16_t)v6.z; tmp.h[3] = (bf16_t)v6.w;
      *(ushort4*)&Xb[row * LDSTR + col] = tmp.u4;
    }
    __syncthreads();

    // issue NEXT session's loads (in flight across compute phases)
    if (it + 1 < NITER) {
      int sn = s + NBLK;
      int snc = (sn < B_SESS) ? sn : (B_SESS - 1);
      const float4* xn = (const float4*)(x + (size_t)snc * (L_SESS * H_DIM));
#pragma unroll
      for (int j = 0; j < 6; ++j) v[j] = xn[t + 256 * j];
      if (t < 64) v6 = xn[1536 + t];
    }

    // u[n] = W1[n] . x_last via broadcast-row MFMA (Xb row 49)
    f32x4 uacc0 = zero4, uacc1 = zero4;
#pragma unroll
    for (int kt = 0; kt < 4; ++kt) {
      bf16x8 av = *(const bf16x8*)&Xb[49 * LDSTR + kt * 32 + q * 8];
      uacc0 = __builtin_amdgcn_mfma_f32_16x16x32_bf16(av, bw1[kt][0], uacc0, 0, 0, 0);
      uacc1 = __builtin_amdgcn_mfma_f32_16x16x32_bf16(av, bw1[kt][1], uacc1, 0, 0, 0);
    }
    const float u0 = uacc0[0] + b0;
    const float u1 = uacc1[0] + b1;

    // GEMM: D[64x32]/wave = Xb(64x128) @ W2^T cols (B in registers)
    f32x4 acc[4][2];
#pragma unroll
    for (int mt = 0; mt < 4; ++mt) { acc[mt][0] = zero4; acc[mt][1] = zero4; }
#pragma unroll
    for (int kt = 0; kt < 4; ++kt) {
      const int ko = kt * 32 + q * 8;
#pragma unroll
      for (int mt = 0; mt < 4; ++mt) {
        bf16x8 a = *(const bf16x8*)&Xb[(mt * 16 + c) * LDSTR + ko];
        acc[mt][0] = __builtin_amdgcn_mfma_f32_16x16x32_bf16(a, bw2[kt][0], acc[mt][0], 0, 0, 0);
        acc[mt][1] = __builtin_amdgcn_mfma_f32_16x16x32_bf16(a, bw2[kt][1], acc[mt][1], 0, 0, 0);
      }
    }

    // epilogue: h=sigmoid(acc+u); c-reduce via DPP row_ror (no DS);
    // 16-way select so each lane keeps exactly one row's partial -> 1 write
    float esel = 0.f;
#pragma unroll
    for (int mt = 0; mt < 4; ++mt) {
#pragma unroll
      for (int r = 0; r < 4; ++r) {
        float t0 = acc[mt][0][r] + u0;
        float t1 = acc[mt][1][r] + u1;
        float h0 = 1.0f / (1.0f + __expf(-t0));
        float h1 = 1.0f / (1.0f + __expf(-t1));
        float p = h0 * qn0 + h1 * qn1;
        p = row16_sum(p);  // all 16 lanes of the q-row now hold the c-sum
        esel = (c == mt * 4 + r) ? p : esel;
      }
    }
    // lane (q,c) holds partial for row = (c>>2)*16 + q*4 + (c&3)
    epart[((c >> 2) * 16 + q * 4 + (c & 3)) * ESTR + wu] = esel;
    __syncthreads();

    // ALL waves redundantly: combine + masked stable softmax; lane == row.
    // alpha stays in registers -> pooling fetches it via v_readlane (SALU).
    float e = qbv;
#pragma unroll
    for (int j = 0; j < 4; ++j) e += epart[lane * ESTR + j];
    float mval = (lane < L_SESS) ? e : -1.0e30f;
    float mx = wave_max(mval);
    float z = (lane < L_SESS) ? __expf(e - mx) : 0.f;
    float d = wave_sum(z);
    float alpha = z / d;

    // pooling: wave wu handles rows m = wu+4k; 2 adjacent cols per lane (b32)
    float p0 = 0.f, p1 = 0.f;
#pragma unroll
    for (int k = 0; k < 13; ++k) {
      int m = wu + 4 * k;  // wave-uniform
      if (m < L_SESS) {
        float am = __int_as_float(
            __builtin_amdgcn_readlane(__float_as_int(alpha), m));
        unsigned int xv2 = *(const unsigned int*)&Xb[m * LDSTR + 2 * lane];
        p0 += am * __uint_as_float(xv2 << 16);
        p1 += am * __uint_as_float(xv2 & 0xFFFF0000u);
      }
    }
    *(float2*)&pool[wu * POOLSTR + 2 * lane] = make_float2(p0, p1);
    __syncthreads();

    // final cross-wave combine + store
    if (t < H_DIM) {
      float r = pool[t] + pool[POOLSTR + t] + pool[2 * POOLSTR + t] +
                pool[3 * POOLSTR + t];
      if (s < B_SESS) out[(size_t)s * H_DIM + t] = r;
    }
    s += NBLK;
  }
}

extern "C" void kernel_launch(void* const* d_in, const int* in_sizes, int n_in,
                              void* d_out, int out_size, void* d_ws, size_t ws_size,
                              hipStream_t stream) {
  const float* x    = (const float*)d_in[0];
  const float* w1   = (const float*)d_in[1];
  const float* w1b  = (const float*)d_in[2];
  const float* w2   = (const float*)d_in[3];
  const float* w2bi = (const float*)d_in[4];
  const float* qw   = (const float*)d_in[5];
  const float* qb   = (const float*)d_in[6];
  fused_attn_kernel<<<NBLK, 256, 0, stream>>>(x, w1, w1b, w2, w2bi, qw, qb,
                                              (float*)d_out);
}

// Round 3
// 373.990 us; speedup vs baseline: 1.0532x; 1.0114x over previous
//
#include <hip/hip_runtime.h>

#define H_DIM 128
#define L_SESS 50
#define B_SESS 10000
#define NBLK 768    // persistent blocks: 3/CU x 256 CU
#define LDSTR 136   // Xb row stride in bf16 elems (128+8 pad)
#define ESTR 5      // epart row stride in floats
#define POOLSTR 132 // pool row stride in floats (128+4 pad)

typedef __bf16 bf16_t;
typedef __bf16 bf16x8 __attribute__((ext_vector_type(8)));
typedef float f32x4 __attribute__((ext_vector_type(4)));

__device__ __forceinline__ bf16x8 cvt_bf8(float4 a, float4 b) {
  bf16x8 r;
  r[0] = (bf16_t)a.x; r[1] = (bf16_t)a.y; r[2] = (bf16_t)a.z; r[3] = (bf16_t)a.w;
  r[4] = (bf16_t)b.x; r[5] = (bf16_t)b.y; r[6] = (bf16_t)b.z; r[7] = (bf16_t)b.w;
  return r;
}

// DPP row_ror reductions: pure-VALU cross-lane within each 16-lane row (no DS)
template <int CTRL>
__device__ __forceinline__ float dpp_add(float x) {
  int tt = __builtin_amdgcn_update_dpp(0, __float_as_int(x), CTRL, 0xF, 0xF, false);
  return x + __int_as_float(tt);
}
template <int CTRL>
__device__ __forceinline__ float dpp_max(float x) {
  int tt = __builtin_amdgcn_update_dpp(0, __float_as_int(x), CTRL, 0xF, 0xF, false);
  return fmaxf(x, __int_as_float(tt));
}
__device__ __forceinline__ float row16_sum(float x) {
  x = dpp_add<0x121>(x); x = dpp_add<0x122>(x);  // row_ror:1, :2
  x = dpp_add<0x124>(x); x = dpp_add<0x128>(x);  // row_ror:4, :8
  return x;
}
__device__ __forceinline__ float wave_sum(float x) {
  x = row16_sum(x);
  x += __shfl_xor(x, 16);
  x += __shfl_xor(x, 32);
  return x;
}
__device__ __forceinline__ float wave_max(float x) {
  x = dpp_max<0x121>(x); x = dpp_max<0x122>(x);
  x = dpp_max<0x124>(x); x = dpp_max<0x128>(x);
  x = fmaxf(x, __shfl_xor(x, 16));
  x = fmaxf(x, __shfl_xor(x, 32));
  return x;
}

// LDS-only barrier: orders LDS (lgkmcnt) but does NOT drain vmcnt, so the
// x-prefetch global loads stay in flight across sync points (m201 pattern).
// All LDS accesses are compiler-visible C++ ops; "memory" + sched_barrier(0)
// pin them on the correct side.
__device__ __forceinline__ void bar_lds() {
  __builtin_amdgcn_sched_barrier(0);
  asm volatile("s_waitcnt lgkmcnt(0)" ::: "memory");
  __builtin_amdgcn_s_barrier();
  __builtin_amdgcn_sched_barrier(0);
}

__global__ __launch_bounds__(256, 3) void fused_attn_kernel(
    const float* __restrict__ x, const float* __restrict__ w1,
    const float* __restrict__ w1b, const float* __restrict__ w2,
    const float* __restrict__ w2bi, const float* __restrict__ qw,
    const float* __restrict__ qb, float* __restrict__ out) {
  __shared__ __attribute__((aligned(16))) unsigned short Xb[64 * LDSTR];
  __shared__ __attribute__((aligned(16))) float epart[64 * ESTR];
  __shared__ __attribute__((aligned(16))) float pool[4 * POOLSTR];

  const int t = threadIdx.x;
  const int lane = t & 63, w = t >> 6, q = lane >> 4, c = lane & 15;
  const int wu = __builtin_amdgcn_readfirstlane(w);  // SGPR wave id
  const int n0 = w * 32 + c, n1 = n0 + 16;

  // exact work split: block bid handles sessions bid + k*NBLK, k < niter.
  // blocks 0..15 -> 14 iters, 16..767 -> 13 iters; sum = exactly B_SESS.
  int s = blockIdx.x;
  const int niter = (B_SESS - s + NBLK - 1) / NBLK;

  // prologue: issue session-s x loads FIRST (HBM latency hides under setup)
  const float4* xv = (const float4*)(x + (size_t)s * (L_SESS * H_DIM));
  float4 v[6];
#pragma unroll
  for (int j = 0; j < 6; ++j) v[j] = xv[t + 256 * j];
  float4 v6;
  if (t < 64) v6 = xv[1536 + t];

  // loop-invariant weight fragments: fp32 global (L2-hot) -> bf16 regs
  bf16x8 bw2[4][2], bw1[4][2];
  const float4* w2v = (const float4*)w2;
  const float4* w1v = (const float4*)w1;
#pragma unroll
  for (int kt = 0; kt < 4; ++kt) {
    const int ko4 = kt * 8 + q * 2;
    bw2[kt][0] = cvt_bf8(w2v[n0 * 32 + ko4], w2v[n0 * 32 + ko4 + 1]);
    bw2[kt][1] = cvt_bf8(w2v[n1 * 32 + ko4], w2v[n1 * 32 + ko4 + 1]);
    bw1[kt][0] = cvt_bf8(w1v[n0 * 32 + ko4], w1v[n0 * 32 + ko4 + 1]);
    bw1[kt][1] = cvt_bf8(w1v[n1 * 32 + ko4], w1v[n1 * 32 + ko4 + 1]);
  }
  const float qn0 = qw[n0], qn1 = qw[n1], qbv = qb[0];
  const float b0 = w1b[n0] + w2bi[n0];
  const float b1 = w1b[n1] + w2bi[n1];

  const f32x4 zero4 = {0.f, 0.f, 0.f, 0.f};

  for (int it = 0; it < niter; ++it) {
    bar_lds();  // prev iter done reading Xb

    // stage prefetch registers -> bf16 LDS (compiler inserts per-reg vmcnt)
#pragma unroll
    for (int j = 0; j < 6; ++j) {
      int i = t + 256 * j;
      int row = i >> 5, col = (i & 31) * 4;
      union { bf16_t h[4]; ushort4 u4; } tmp;
      tmp.h[0] = (bf16_t)v[j].x; tmp.h[1] = (bf16_t)v[j].y;
      tmp.h[2] = (bf16_t)v[j].z; tmp.h[3] = (bf16_t)v[j].w;
      *(ushort4*)&Xb[row * LDSTR + col] = tmp.u4;
    }
    if (t < 64) {
      int i = 1536 + t;
      int row = i >> 5, col = (i & 31) * 4;
      union { bf16_t h[4]; ushort4 u4; } tmp;
      tmp.h[0] = (bf16_t)v6.x; tmp.h[1] = (bf16_t)v6.y;
      tmp.h[2] = (bf16_t)v6.z; tmp.h[3] = (bf16_t)v6.w;
      *(ushort4*)&Xb[row * LDSTR + col] = tmp.u4;
    }
    bar_lds();

    // issue NEXT session's loads: stay in flight across ALL following
    // barriers (no vmcnt drain), consumed at next iter's stage phase
    if (it + 1 < niter) {
      int sn = s + NBLK;  // < B_SESS by construction of niter
      const float4* xn = (const float4*)(x + (size_t)sn * (L_SESS * H_DIM));
#pragma unroll
      for (int j = 0; j < 6; ++j) v[j] = xn[t + 256 * j];
      if (t < 64) v6 = xn[1536 + t];
    }

    // u[n] = W1[n] . x_last via broadcast-row MFMA (Xb row 49)
    f32x4 uacc0 = zero4, uacc1 = zero4;
#pragma unroll
    for (int kt = 0; kt < 4; ++kt) {
      bf16x8 av = *(const bf16x8*)&Xb[49 * LDSTR + kt * 32 + q * 8];
      uacc0 = __builtin_amdgcn_mfma_f32_16x16x32_bf16(av, bw1[kt][0], uacc0, 0, 0, 0);
      uacc1 = __builtin_amdgcn_mfma_f32_16x16x32_bf16(av, bw1[kt][1], uacc1, 0, 0, 0);
    }
    const float u0 = uacc0[0] + b0;
    const float u1 = uacc1[0] + b1;

    // GEMM: D[64x32]/wave = Xb(64x128) @ W2^T cols (B in registers)
    f32x4 acc[4][2];
#pragma unroll
    for (int mt = 0; mt < 4; ++mt) { acc[mt][0] = zero4; acc[mt][1] = zero4; }
#pragma unroll
    for (int kt = 0; kt < 4; ++kt) {
      const int ko = kt * 32 + q * 8;
#pragma unroll
      for (int mt = 0; mt < 4; ++mt) {
        bf16x8 a = *(const bf16x8*)&Xb[(mt * 16 + c) * LDSTR + ko];
        acc[mt][0] = __builtin_amdgcn_mfma_f32_16x16x32_bf16(a, bw2[kt][0], acc[mt][0], 0, 0, 0);
        acc[mt][1] = __builtin_amdgcn_mfma_f32_16x16x32_bf16(a, bw2[kt][1], acc[mt][1], 0, 0, 0);
      }
    }

    // epilogue: h=sigmoid(acc+u); c-reduce via DPP row_ror (no DS);
    // 16-way select so each lane keeps exactly one row's partial -> 1 write
    float esel = 0.f;
#pragma unroll
    for (int mt = 0; mt < 4; ++mt) {
#pragma unroll
      for (int r = 0; r < 4; ++r) {
        float t0 = acc[mt][0][r] + u0;
        float t1 = acc[mt][1][r] + u1;
        float h0 = 1.0f / (1.0f + __expf(-t0));
        float h1 = 1.0f / (1.0f + __expf(-t1));
        float p = h0 * qn0 + h1 * qn1;
        p = row16_sum(p);  // all 16 lanes of the q-row now hold the c-sum
        esel = (c == mt * 4 + r) ? p : esel;
      }
    }
    // lane (q,c) holds partial for row = (c>>2)*16 + q*4 + (c&3)
    epart[((c >> 2) * 16 + q * 4 + (c & 3)) * ESTR + wu] = esel;
    bar_lds();

    // ALL waves redundantly: combine + masked stable softmax; lane == row.
    float e = qbv;
#pragma unroll
    for (int j = 0; j < 4; ++j) e += epart[lane * ESTR + j];
    float mval = (lane < L_SESS) ? e : -1.0e30f;
    float mx = wave_max(mval);
    float z = (lane < L_SESS) ? __expf(e - mx) : 0.f;
    float d = wave_sum(z);
    float alpha = z / d;

    // pooling: wave wu handles rows m = wu+4k; 2 adjacent cols per lane (b32)
    float p0 = 0.f, p1 = 0.f;
#pragma unroll
    for (int k = 0; k < 13; ++k) {
      int m = wu + 4 * k;  // wave-uniform
      if (m < L_SESS) {
        float am = __int_as_float(
            __builtin_amdgcn_readlane(__float_as_int(alpha), m));
        unsigned int xv2 = *(const unsigned int*)&Xb[m * LDSTR + 2 * lane];
        p0 += am * __uint_as_float(xv2 << 16);
        p1 += am * __uint_as_float(xv2 & 0xFFFF0000u);
      }
    }
    *(float2*)&pool[wu * POOLSTR + 2 * lane] = make_float2(p0, p1);
    bar_lds();

    // final cross-wave combine + store
    if (t < H_DIM) {
      float r = pool[t] + pool[POOLSTR + t] + pool[2 * POOLSTR + t] +
                pool[3 * POOLSTR + t];
      out[(size_t)s * H_DIM + t] = r;
    }
    s += NBLK;
  }
}

extern "C" void kernel_launch(void* const* d_in, const int* in_sizes, int n_in,
                              void* d_out, int out_size, void* d_ws, size_t ws_size,
                              hipStream_t stream) {
  const float* x    = (const float*)d_in[0];
  const float* w1   = (const float*)d_in[1];
  const float* w1b  = (const float*)d_in[2];
  const float* w2   = (const float*)d_in[3];
  const float* w2bi = (const float*)d_in[4];
  const float* qw   = (const float*)d_in[5];
  const float* qb   = (const float*)d_in[6];
  fused_attn_kernel<<<NBLK, 256, 0, stream>>>(x, w1, w1b, w2, w2bi, qw, qb,
                                              (float*)d_out);
}